// Round 5
// baseline (286.254 us; speedup 1.0000x reference)
//
#include <hip/hip_runtime.h>
#include <math.h>

namespace {

constexpr int Himg = 224, Wimg = 224, Cn = 3, Kk = 32;
constexpr int MAXT = 64;
constexpr int WSTRIDE = 512;               // ints per image in tap workspace
constexpr int IMG_F  = Himg * Wimg * Cn;   // 150528 floats per image
constexpr int ROW_F  = Wimg * Cn;          // 672 floats per row
constexpr int ROW_B  = ROW_F * 4;          // 2688 B

// ---- tiled LDS structure ----
// R1-R4 evidence: per-CU vector-memory fetch rate saturates at ~14 B/cyc/CU
// regardless of per-wave MLP (R1/R2/R4) or TLP (R3). Only traffic reduction
// helps: stage each input tile ONCE into LDS, serve the ~16x tap reuse from
// the LDS pipe (no MSHR pressure). Tap traffic 1.03 GB -> 217 MB staged.
constexpr int TW = 56;                     // output chunk-cols per tile (168 = 3*56)
constexpr int TH = 32;                     // output rows per tile (224 = 7*32)
constexpr int TILES_X = 3;
constexpr int TILES_Y = 7;
constexpr int TPI = TILES_X * TILES_Y;     // 21 tiles per image
constexpr int L_W = 320;                   // LDS floats/row: 4*56 + 93 -> pad to 320
constexpr int L_H = TH + 31;               // 63 rows (dky in [-15,16])
constexpr int L_SZ = L_W * L_H;            // 20160 floats = 80640 B
constexpr int OUT_PT = (TW * TH) / 256;    // 7 outputs per thread

typedef float v4  __attribute__((ext_vector_type(4), aligned(4)));
typedef float v4a __attribute__((ext_vector_type(4), aligned(16)));

// ws per-image layout (ints): [0]=n  [1]=w  [2..65]=dky  [66..129]=dkx  [130..193]=xoff(bytes)

// ---------------- pre-pass: one tap list per image ----------------
__global__ __launch_bounds__(64)
void build_taps(const float* __restrict__ tbl,
                const int* __restrict__ amt,
                const int* __restrict__ ang,
                int* __restrict__ ws)
{
    const int b   = blockIdx.x;
    const int tid = threadIdx.x;

    __shared__ int   s_cnt;
    __shared__ float s_w;
    __shared__ int   s_dky[MAXT], s_dkx[MAXT];

    if (tid == 0) { s_cnt = 0; s_w = 0.0f; }
    __syncthreads();

    const int a = amt[b];
    // reference-exact numerics (verified absmax 0.0039 across all prior rounds)
    const float  rad = (float)ang[b] * (float)(M_PI / 180.0);
    const double rd  = (double)rad;
    const float  cth = (float)cos(rd);
    const float  sth = (float)sin(rd);
    const float  e   = 31.0f;
    const float xoff = __fmul_rn(__fsub_rn(e, __fsub_rn(__fmul_rn(cth, e), __fmul_rn(sth, e))), 0.5f);
    const float yoff = __fmul_rn(__fsub_rn(e, __fadd_rn(__fmul_rn(sth, e), __fmul_rn(cth, e))), 0.5f);

    for (int p = tid; p < Kk * Kk; p += 64) {
        const int   ky = p >> 5, kx = p & 31;
        const float xf = (float)kx, yf = (float)ky;
        const float sx = __fadd_rn(__fsub_rn(__fmul_rn(cth, xf), __fmul_rn(sth, yf)), xoff);
        const float sy = __fadd_rn(__fadd_rn(__fmul_rn(sth, xf), __fmul_rn(cth, yf)), yoff);
        const int ix = (int)rintf(sx);   // round-half-even == jnp.round
        const int iy = (int)rintf(sy);
        if (ix >= 0 && ix < Kk && iy >= 0 && iy < Kk) {
            const float v = tbl[((a * Kk + iy) * Kk + ix) * Cn];
            if (v != 0.0f) {
                const int idx = atomicAdd(&s_cnt, 1);
                if (idx < MAXT) {
                    s_dky[idx] = ky - 15;
                    s_dkx[idx] = kx - 15;
                    s_w = v;                 // benign race: all writers store 1/size
                }
            }
        }
    }
    __syncthreads();

    const int n = min(s_cnt, MAXT);
    int* wsb = ws + b * WSTRIDE;
    if (tid == 0) { wsb[0] = n; wsb[1] = __float_as_int(s_w); }
    for (int i = tid; i < n; i += 64) {
        wsb[2 + i]   = s_dky[i];
        wsb[66 + i]  = s_dkx[i];
        wsb[130 + i] = s_dky[i] * ROW_B + s_dkx[i] * (int)(Cn * sizeof(float));
    }
}

// ---------------- LDS-tiled conv ----------------
// Zero-padded LDS tile => NO edge masks anywhere in the compute loop; OOB taps
// add 0.0 (bitwise-identical to the masked adds of R0-R4). Tap x-shift is
// 3*dkx floats (12B): shift mod 4 floats is WAVE-UNIFORM per tap -> scalar
// 4-way branch; misaligned cases use two aligned ds_read_b128 + static
// component picks (no extra VALU in the adds).
__global__ __launch_bounds__(256, 2)
void blur_lds(const float* __restrict__ x,
              const int* __restrict__ ws,
              float* __restrict__ out,
              int B)
{
    const int tid = threadIdx.x;
    const int L   = blockIdx.x;

    // XCD-pinned decode: image b handled entirely by XCD (b & 7). 2688 = 8*336.
    int b, t;
    if (B == 128) {
        const int xcd = L & 7;
        const int j   = L >> 3;
        const int g   = j / TPI;
        t = j - g * TPI;
        b = g * 8 + xcd;
    } else {
        b = L / TPI;
        t = L - b * TPI;
    }
    const int ty = t / TILES_X;            // 0..6
    const int tx = t - ty * TILES_X;       // 0..2
    const int y0 = ty * TH;                // first output row of tile
    const int k0 = tx * TW;                // first output chunk-col of tile
    const int g0 = 4 * k0 - 48;            // global float-col of LDS col 0 (mult of 4)
    const int r0 = y0 - 15;                // global row of LDS row 0

    __shared__ float lds[L_SZ];            // 80640 B
    __shared__ int   shNW[2];
    __shared__ int   s_dky[MAXT], s_dkx[MAXT];

    const int* wsb = ws + b * WSTRIDE;
    if (tid < 2)    shNW[tid]  = wsb[tid];
    if (tid < MAXT) {
        s_dky[tid] = wsb[2 + tid];
        s_dkx[tid] = wsb[66 + tid];
    }

    // ---- stage tile: 63 rows x 80 v4-chunks, zero-padded outside the image ----
    const float* xb = x + (size_t)b * IMG_F;
    for (int u = tid; u < L_H * 80; u += 256) {
        const int lr  = u / 80;
        const int lc4 = (u - lr * 80) * 4;         // LDS float col, multiple of 4
        const int gr  = r0 + lr;
        const int gc  = g0 + lc4;                  // multiple of 4; 672 mult of 4
        v4 val = {0.0f, 0.0f, 0.0f, 0.0f};
        if ((unsigned)gr < (unsigned)Himg && (unsigned)gc < (unsigned)ROW_F)
            val = *(const v4a*)(xb + (size_t)gr * ROW_F + gc);
        *(v4a*)(&lds[lr * L_W + lc4]) = val;
    }
    __syncthreads();

    const int   n = shNW[0];
    const float w = __int_as_float(shNW[1]);

    // 7 outputs per thread: o = tid + 256*p -> (r = o/56, c = o%56).
    // lbase = LDS float index of this output's own (dk=0) chunk; mult of 4.
    int lbase[OUT_PT];
#pragma unroll
    for (int p = 0; p < OUT_PT; ++p) {
        const int o = tid + 256 * p;
        const int r = o / TW;
        const int c = o - r * TW;
        lbase[p] = (r + 15) * L_W + 4 * c + 48;
    }

    v4 acc[OUT_PT];
#pragma unroll
    for (int p = 0; p < OUT_PT; ++p) acc[p] = v4{0.0f, 0.0f, 0.0f, 0.0f};

    for (int i = 0; i < n; ++i) {
        // taps are per-image scalars: force SGPR so the 4-way branch is scalar
        const int dky  = __builtin_amdgcn_readfirstlane(s_dky[i]);
        const int dkx  = __builtin_amdgcn_readfirstlane(s_dkx[i]);
        const int toff = dky * L_W + 3 * dkx;      // float offset of tap
        const int s    = toff & 3;                 // shift within aligned v4
        const int ta   = toff - s;                 // aligned scalar offset

        if (s == 0) {
#pragma unroll
            for (int p = 0; p < OUT_PT; ++p) {
                const v4 f = *(const v4a*)(&lds[lbase[p] + ta]);
                acc[p].x += f.x; acc[p].y += f.y; acc[p].z += f.z; acc[p].w += f.w;
            }
        } else if (s == 1) {
#pragma unroll
            for (int p = 0; p < OUT_PT; ++p) {
                const v4 A = *(const v4a*)(&lds[lbase[p] + ta]);
                const v4 Bv = *(const v4a*)(&lds[lbase[p] + ta + 4]);
                acc[p].x += A.y; acc[p].y += A.z; acc[p].z += A.w; acc[p].w += Bv.x;
            }
        } else if (s == 2) {
#pragma unroll
            for (int p = 0; p < OUT_PT; ++p) {
                const v4 A = *(const v4a*)(&lds[lbase[p] + ta]);
                const v4 Bv = *(const v4a*)(&lds[lbase[p] + ta + 4]);
                acc[p].x += A.z; acc[p].y += A.w; acc[p].z += Bv.x; acc[p].w += Bv.y;
            }
        } else {
#pragma unroll
            for (int p = 0; p < OUT_PT; ++p) {
                const v4 A = *(const v4a*)(&lds[lbase[p] + ta]);
                const v4 Bv = *(const v4a*)(&lds[lbase[p] + ta + 4]);
                acc[p].x += A.w; acc[p].y += Bv.x; acc[p].z += Bv.y; acc[p].w += Bv.z;
            }
        }
    }

    // ---- store: coalesced nontemporal b128 ----
    float* ob = out + (size_t)b * IMG_F + (size_t)y0 * ROW_F + 4 * k0;
#pragma unroll
    for (int p = 0; p < OUT_PT; ++p) {
        const int o = tid + 256 * p;
        const int r = o / TW;
        const int c = o - r * TW;
        __builtin_nontemporal_store(
            v4a{acc[p].x * w, acc[p].y * w, acc[p].z * w, acc[p].w * w},
            (v4a*)(ob + r * ROW_F + 4 * c));
    }
}

}  // namespace

extern "C" void kernel_launch(void* const* d_in, const int* in_sizes, int n_in,
                              void* d_out, int out_size, void* d_ws, size_t ws_size,
                              hipStream_t stream) {
    const float* x   = (const float*)d_in[0];
    const float* tbl = (const float*)d_in[1];
    const int*   amt = (const int*)d_in[2];
    const int*   ang = (const int*)d_in[3];
    float*       out = (float*)d_out;
    int*         ws  = (int*)d_ws;

    const int B = in_sizes[2];  // 128

    build_taps<<<B, 64, 0, stream>>>(tbl, amt, ang, ws);
    blur_lds<<<B * TPI, 256, 0, stream>>>(x, ws, out, B);
}

// Round 6
// 219.328 us; speedup vs baseline: 1.3051x; 1.3051x over previous
//
#include <hip/hip_runtime.h>
#include <math.h>

namespace {

constexpr int Himg = 224, Wimg = 224, Cn = 3, Kk = 32;
constexpr int MAXT = 64;
constexpr int WSTRIDE = 512;               // ints per image in tap workspace
constexpr int IMG_F  = Himg * Wimg * Cn;   // 150528 floats per image
constexpr int ROW_F  = Wimg * Cn;          // 672 floats per row
constexpr int ROW_B  = ROW_F * 4;          // 2688 B

// ---- tiled LDS structure (R5 concept, R6 conflict-free access pattern) ----
// R5 post-mortem: ds_read_b128 at lane-stride 16B with row-straddle = ~18
// extra cyc/read (3.9e7 conflicts). m136-verified free pattern is b32 at
// lane-stride 4B (2 lanes/bank). So: scalar floats, wave = 64 contiguous.
constexpr int TW_F = 224;                  // float-cols per tile (672 = 3*224)
constexpr int TH = 32;                     // output rows per tile (224 = 7*32)
constexpr int TILES_X = 3;
constexpr int TILES_Y = 7;
constexpr int TPI = TILES_X * TILES_Y;     // 21 tiles per image
constexpr int L_W = 320;                   // LDS floats/row: 224 + 2*48 halo = 320
                                           // L_W%32==0 and (L_W-TW_F)%32==0 ->
                                           // row-wrap preserves 2-lanes/bank
constexpr int L_H = TH + 31;               // 63 rows (dky in [-15,16])
constexpr int L_SZ = L_W * L_H;            // 20160 floats = 80640 B
constexpr int OUT_PT = (TW_F * TH) / 256;  // 28 scalar outputs per thread

typedef float v4  __attribute__((ext_vector_type(4), aligned(4)));
typedef float v4a __attribute__((ext_vector_type(4), aligned(16)));

// ws per-image layout (ints): [0]=n  [1]=w  [2..65]=dky  [66..129]=dkx  [130..193]=xoff(bytes)

// ---------------- pre-pass: one tap list per image ----------------
__global__ __launch_bounds__(64)
void build_taps(const float* __restrict__ tbl,
                const int* __restrict__ amt,
                const int* __restrict__ ang,
                int* __restrict__ ws)
{
    const int b   = blockIdx.x;
    const int tid = threadIdx.x;

    __shared__ int   s_cnt;
    __shared__ float s_w;
    __shared__ int   s_dky[MAXT], s_dkx[MAXT];

    if (tid == 0) { s_cnt = 0; s_w = 0.0f; }
    __syncthreads();

    const int a = amt[b];
    // reference-exact numerics (verified absmax 0.0039 across all prior rounds)
    const float  rad = (float)ang[b] * (float)(M_PI / 180.0);
    const double rd  = (double)rad;
    const float  cth = (float)cos(rd);
    const float  sth = (float)sin(rd);
    const float  e   = 31.0f;
    const float xoff = __fmul_rn(__fsub_rn(e, __fsub_rn(__fmul_rn(cth, e), __fmul_rn(sth, e))), 0.5f);
    const float yoff = __fmul_rn(__fsub_rn(e, __fadd_rn(__fmul_rn(sth, e), __fmul_rn(cth, e))), 0.5f);

    for (int p = tid; p < Kk * Kk; p += 64) {
        const int   ky = p >> 5, kx = p & 31;
        const float xf = (float)kx, yf = (float)ky;
        const float sx = __fadd_rn(__fsub_rn(__fmul_rn(cth, xf), __fmul_rn(sth, yf)), xoff);
        const float sy = __fadd_rn(__fadd_rn(__fmul_rn(sth, xf), __fmul_rn(cth, yf)), yoff);
        const int ix = (int)rintf(sx);   // round-half-even == jnp.round
        const int iy = (int)rintf(sy);
        if (ix >= 0 && ix < Kk && iy >= 0 && iy < Kk) {
            const float v = tbl[((a * Kk + iy) * Kk + ix) * Cn];
            if (v != 0.0f) {
                const int idx = atomicAdd(&s_cnt, 1);
                if (idx < MAXT) {
                    s_dky[idx] = ky - 15;
                    s_dkx[idx] = kx - 15;
                    s_w = v;                 // benign race: all writers store 1/size
                }
            }
        }
    }
    __syncthreads();

    const int n = min(s_cnt, MAXT);
    int* wsb = ws + b * WSTRIDE;
    if (tid == 0) { wsb[0] = n; wsb[1] = __float_as_int(s_w); }
    for (int i = tid; i < n; i += 64) {
        wsb[2 + i]   = s_dky[i];
        wsb[66 + i]  = s_dkx[i];
        wsb[130 + i] = s_dky[i] * ROW_B + s_dkx[i] * (int)(Cn * sizeof(float));
    }
}

// ---------------- LDS-tiled conv, scalar b32 reads (conflict-free) ----------------
// Zero-padded LDS tile => no edge masks; OOB taps add 0.0 (bitwise-identical
// to the masked adds of R0-R4). Per tap: wave-uniform byte offset added to 28
// per-thread base addresses; 28 independent acc chains (R3-proven MLP).
__global__ __launch_bounds__(256, 2)
void blur_lds32(const float* __restrict__ x,
                const int* __restrict__ ws,
                float* __restrict__ out,
                int B)
{
    const int tid = threadIdx.x;
    const int L   = blockIdx.x;

    // XCD-pinned decode: image b handled entirely by XCD (b & 7). 2688 = 8*336.
    int b, t;
    if (B == 128) {
        const int xcd = L & 7;
        const int j   = L >> 3;
        const int g   = j / TPI;
        t = j - g * TPI;
        b = g * 8 + xcd;
    } else {
        b = L / TPI;
        t = L - b * TPI;
    }
    const int ty = t / TILES_X;            // 0..6
    const int tx = t - ty * TILES_X;       // 0..2
    const int y0 = ty * TH;                // first output row of tile
    const int g0 = tx * TW_F - 48;         // global float-col of LDS col 0 (mult of 4)
    const int r0 = y0 - 15;                // global row of LDS row 0

    __shared__ float lds[L_SZ];            // 80640 B
    __shared__ int   shNW[2];
    __shared__ int   s_tof[MAXT];          // per-tap LDS byte offset

    const int* wsb = ws + b * WSTRIDE;
    if (tid < 2)    shNW[tid] = wsb[tid];
    if (tid < MAXT) {
        const int dky = wsb[2 + tid];
        const int dkx = wsb[66 + tid];
        s_tof[tid] = (dky * L_W + 3 * dkx) * 4;   // bytes
    }

    // ---- stage tile: 63 rows x 80 v4-chunks, zero-padded outside the image ----
    const float* xb = x + (size_t)b * IMG_F;
    for (int u = tid; u < L_H * 80; u += 256) {
        const int lr  = u / 80;
        const int lc4 = (u - lr * 80) * 4;         // LDS float col, multiple of 4
        const int gr  = r0 + lr;
        const int gc  = g0 + lc4;                  // multiple of 4
        v4 val = {0.0f, 0.0f, 0.0f, 0.0f};
        if ((unsigned)gr < (unsigned)Himg && (unsigned)gc < (unsigned)ROW_F)
            val = *(const v4a*)(xb + (size_t)gr * ROW_F + gc);
        *(v4a*)(&lds[lr * L_W + lc4]) = val;
    }
    __syncthreads();

    const int   n = shNW[0];
    const float w = __int_as_float(shNW[1]);

    // 28 scalar outputs/thread: phi = p*256 + tid -> (r = phi/224, c = phi%224).
    // Wave reads 64 CONSECUTIVE floats per p (stride-4B lanes = 2/bank, free;
    // row-wrap jump = 96 words == 0 mod 32 -> pattern preserved).
    int lbB[OUT_PT];
#pragma unroll
    for (int p = 0; p < OUT_PT; ++p) {
        const int phi = p * 256 + tid;
        const int r   = phi / TW_F;
        const int c   = phi - r * TW_F;
        lbB[p] = ((r + 15) * L_W + (c + 48)) * 4;  // bytes
    }

    float acc[OUT_PT];
#pragma unroll
    for (int p = 0; p < OUT_PT; ++p) acc[p] = 0.0f;

    const char* ldsb = (const char*)lds;
    for (int i = 0; i < n; ++i) {
        const int tof = __builtin_amdgcn_readfirstlane(s_tof[i]);  // wave-uniform
#pragma unroll
        for (int p = 0; p < OUT_PT; ++p) {
            acc[p] += *(const float*)(ldsb + (lbB[p] + tof));
        }
    }

    // ---- store: wave-contiguous scalar nontemporal stores ----
    float* ob = out + (size_t)b * IMG_F + (size_t)y0 * ROW_F + tx * TW_F;
#pragma unroll
    for (int p = 0; p < OUT_PT; ++p) {
        const int phi = p * 256 + tid;
        const int r   = phi / TW_F;
        const int c   = phi - r * TW_F;
        __builtin_nontemporal_store(acc[p] * w, ob + r * ROW_F + c);
    }
}

}  // namespace

extern "C" void kernel_launch(void* const* d_in, const int* in_sizes, int n_in,
                              void* d_out, int out_size, void* d_ws, size_t ws_size,
                              hipStream_t stream) {
    const float* x   = (const float*)d_in[0];
    const float* tbl = (const float*)d_in[1];
    const int*   amt = (const int*)d_in[2];
    const int*   ang = (const int*)d_in[3];
    float*       out = (float*)d_out;
    int*         ws  = (int*)d_ws;

    const int B = in_sizes[2];  // 128

    build_taps<<<B, 64, 0, stream>>>(tbl, amt, ang, ws);
    blur_lds32<<<B * TPI, 256, 0, stream>>>(x, ws, out, B);
}

// Round 7
// 210.478 us; speedup vs baseline: 1.3600x; 1.0420x over previous
//
#include <hip/hip_runtime.h>
#include <math.h>

namespace {

constexpr int Himg = 224, Wimg = 224, Cn = 3, Kk = 32;
constexpr int MAXT = 64;
constexpr int WSTRIDE = 512;               // ints per image in tap workspace
constexpr int IMG_F  = Himg * Wimg * Cn;   // 150528 floats per image
constexpr int ROW_F  = Wimg * Cn;          // 672 floats per row
constexpr int ROW_B  = ROW_F * 4;          // 2688 B

// ---- tiled LDS structure, lane=col / p=row mapping ----
// R6 evidence: b32 @ lane-stride-4B = 0 conflicts, but per-tap serialization
// (s_tof LDS load + drain + 28 runtime addr-adds) starved the LDS pipe (40%
// util, 112 us). Fix: outputs per thread = 32 ROWS of one column -> p-stride
// in LDS is the constant 1280 B -> ds_read_b32 offset:imm, ONE v_add per tap.
constexpr int TW_F = 224;                  // tile width in float-cols (672 = 3*224)
constexpr int TH = 32;                     // output rows per tile (224 = 7*32)
constexpr int TILES_X = 3;
constexpr int TILES_Y = 7;
constexpr int TPI = TILES_X * TILES_Y;     // 21 tiles per image
constexpr int L_W = 320;                   // 224 + 2*48 halo
constexpr int L_H = TH + 31;               // 63 rows (dky in [-15,16])
constexpr int L_SZ = L_W * L_H;            // 20160 floats = 80640 B

typedef float v4  __attribute__((ext_vector_type(4), aligned(4)));
typedef float v4a __attribute__((ext_vector_type(4), aligned(16)));

// ws per-image layout (ints): [0]=n  [1]=w  [2..65]=dky  [66..129]=dkx  [130..193]=xoff(bytes)

// ---------------- pre-pass: one tap list per image ----------------
__global__ __launch_bounds__(64)
void build_taps(const float* __restrict__ tbl,
                const int* __restrict__ amt,
                const int* __restrict__ ang,
                int* __restrict__ ws)
{
    const int b   = blockIdx.x;
    const int tid = threadIdx.x;

    __shared__ int   s_cnt;
    __shared__ float s_w;
    __shared__ int   s_dky[MAXT], s_dkx[MAXT];

    if (tid == 0) { s_cnt = 0; s_w = 0.0f; }
    __syncthreads();

    const int a = amt[b];
    // reference-exact numerics (verified absmax 0.0039 across all prior rounds)
    const float  rad = (float)ang[b] * (float)(M_PI / 180.0);
    const double rd  = (double)rad;
    const float  cth = (float)cos(rd);
    const float  sth = (float)sin(rd);
    const float  e   = 31.0f;
    const float xoff = __fmul_rn(__fsub_rn(e, __fsub_rn(__fmul_rn(cth, e), __fmul_rn(sth, e))), 0.5f);
    const float yoff = __fmul_rn(__fsub_rn(e, __fadd_rn(__fmul_rn(sth, e), __fmul_rn(cth, e))), 0.5f);

    for (int p = tid; p < Kk * Kk; p += 64) {
        const int   ky = p >> 5, kx = p & 31;
        const float xf = (float)kx, yf = (float)ky;
        const float sx = __fadd_rn(__fsub_rn(__fmul_rn(cth, xf), __fmul_rn(sth, yf)), xoff);
        const float sy = __fadd_rn(__fadd_rn(__fmul_rn(sth, xf), __fmul_rn(cth, yf)), yoff);
        const int ix = (int)rintf(sx);   // round-half-even == jnp.round
        const int iy = (int)rintf(sy);
        if (ix >= 0 && ix < Kk && iy >= 0 && iy < Kk) {
            const float v = tbl[((a * Kk + iy) * Kk + ix) * Cn];
            if (v != 0.0f) {
                const int idx = atomicAdd(&s_cnt, 1);
                if (idx < MAXT) {
                    s_dky[idx] = ky - 15;
                    s_dkx[idx] = kx - 15;
                    s_w = v;                 // benign race: all writers store 1/size
                }
            }
        }
    }
    __syncthreads();

    const int n = min(s_cnt, MAXT);
    int* wsb = ws + b * WSTRIDE;
    if (tid == 0) { wsb[0] = n; wsb[1] = __float_as_int(s_w); }
    for (int i = tid; i < n; i += 64) {
        wsb[2 + i]   = s_dky[i];
        wsb[66 + i]  = s_dkx[i];
        wsb[130 + i] = s_dky[i] * ROW_B + s_dkx[i] * (int)(Cn * sizeof(float));
    }
}

// ---------------- LDS-tiled conv, column-per-lane / static row offsets ----------------
// Zero-padded LDS tile => no masks in compute; OOB taps add 0.0 (bitwise-
// identical to masked adds). Per tap: ONE v_add (base + wave-uniform tof),
// then 32x { ds_read_b32 offset:p*1280 ; v_add_f32 }. Lane-stride 4B per
// instruction (2 lanes/bank, measured free in R6); all lanes same row ->
// no row-wrap. Tap offsets prefetched one ahead (in-order DS completion
// lets the drain overlap the 32 data reads).
__global__ __launch_bounds__(256, 2)
void blur_col(const float* __restrict__ x,
              const int* __restrict__ ws,
              float* __restrict__ out,
              int B)
{
    const int tid = threadIdx.x;
    const int L   = blockIdx.x;

    // XCD-pinned decode: image b handled entirely by XCD (b & 7). 2688 = 8*336.
    int b, t;
    if (B == 128) {
        const int xcd = L & 7;
        const int j   = L >> 3;
        const int g   = j / TPI;
        t = j - g * TPI;
        b = g * 8 + xcd;
    } else {
        b = L / TPI;
        t = L - b * TPI;
    }
    const int ty = t / TILES_X;            // 0..6
    const int tx = t - ty * TILES_X;       // 0..2
    const int y0 = ty * TH;                // first output row of tile
    const int g0 = tx * TW_F - 48;         // global float-col of LDS col 0 (mult of 4)
    const int r0 = y0 - 15;                // global row of LDS row 0

    __shared__ float lds[L_SZ];            // 80640 B
    __shared__ int   shNW[2];
    __shared__ int   s_tof[MAXT + 1];      // per-tap LDS byte offset (+1 for prefetch)

    const int* wsb = ws + b * WSTRIDE;
    if (tid < 2)    shNW[tid] = wsb[tid];
    if (tid < MAXT) {
        const int dky = wsb[2 + tid];
        const int dkx = wsb[66 + tid];
        s_tof[tid] = (dky * L_W + 3 * dkx) * 4;   // bytes
    }

    // ---- stage tile: 63 rows x 80 v4-chunks, zero-padded outside the image ----
    const float* xb = x + (size_t)b * IMG_F;
    for (int u = tid; u < L_H * 80; u += 256) {
        const int lr  = u / 80;
        const int lc4 = (u - lr * 80) * 4;         // LDS float col, multiple of 4
        const int gr  = r0 + lr;
        const int gc  = g0 + lc4;                  // multiple of 4
        v4 val = {0.0f, 0.0f, 0.0f, 0.0f};
        if ((unsigned)gr < (unsigned)Himg && (unsigned)gc < (unsigned)ROW_F)
            val = *(const v4a*)(xb + (size_t)gr * ROW_F + gc);
        *(v4a*)(&lds[lr * L_W + lc4]) = val;
    }
    __syncthreads();

    const int   n = shNW[0];
    const float w = __int_as_float(shNW[1]);

    if (tid < TW_F) {                      // 224 active threads; 32 idle (wave-3 hi)
        const char* ldsb = (const char*)lds;
        const int   abase = (15 * L_W + 48 + tid) * 4;   // row 15, own col, bytes

        float acc[TH];
#pragma unroll
        for (int p = 0; p < TH; ++p) acc[p] = 0.0f;

        int tofn = s_tof[0];
        for (int i = 0; i < n; ++i) {
            const int tof = __builtin_amdgcn_readfirstlane(tofn);  // wave-uniform
            tofn = s_tof[i + 1];                  // prefetch next (broadcast read)
            const char* ap = ldsb + (abase + tof);
#pragma unroll
            for (int p = 0; p < TH; ++p) {
                acc[p] += *(const float*)(ap + p * (L_W * 4));   // static offset imm
            }
        }

        // ---- store: per instruction, lanes = consecutive cols (coalesced) ----
        float* ob = out + (size_t)b * IMG_F + (size_t)y0 * ROW_F + tx * TW_F + tid;
#pragma unroll
        for (int p = 0; p < TH; ++p) {
            __builtin_nontemporal_store(acc[p] * w, ob + p * ROW_F);
        }
    }
}

}  // namespace

extern "C" void kernel_launch(void* const* d_in, const int* in_sizes, int n_in,
                              void* d_out, int out_size, void* d_ws, size_t ws_size,
                              hipStream_t stream) {
    const float* x   = (const float*)d_in[0];
    const float* tbl = (const float*)d_in[1];
    const int*   amt = (const int*)d_in[2];
    const int*   ang = (const int*)d_in[3];
    float*       out = (float*)d_out;
    int*         ws  = (int*)d_ws;

    const int B = in_sizes[2];  // 128

    build_taps<<<B, 64, 0, stream>>>(tbl, amt, ang, ws);
    blur_col<<<B * TPI, 256, 0, stream>>>(x, ws, out, B);
}